// Round 1
// 3591.099 us; speedup vs baseline: 11.0185x; 11.0185x over previous
//
#include <hip/hip_runtime.h>
#include <hip/hip_bf16.h>

#define DI __device__ __forceinline__

constexpr int S_ = 2048;
constexpr int D_ = 1024;
constexpr int H_ = 16;
constexpr int HD_ = 64;
constexpr int BH_ = 32;      // B*H
constexpr int NKEEP = 675;   // max(int(2048*0.33), 2)

DI float wsum(float v) {
#pragma unroll
  for (int o = 32; o > 0; o >>= 1) v += __shfl_xor(v, o, 64);
  return v;
}
DI float wmaxr(float v) {
#pragma unroll
  for (int o = 32; o > 0; o >>= 1) v = fmaxf(v, __shfl_xor(v, o, 64));
  return v;
}
DI float wminr(float v) {
#pragma unroll
  for (int o = 32; o > 0; o >>= 1) v = fminf(v, __shfl_xor(v, o, 64));
  return v;
}

// ---------------------------------------------------------------------------
// K1: qkv = x @ qkv_w^T + qkv_b, scattered to q/k/v (B,H,S,64) f32
// ---------------------------------------------------------------------------
__global__ __launch_bounds__(256) void k_gemm_qkv(
    const float* __restrict__ x, const float* __restrict__ w,
    const float* __restrict__ bias, float* __restrict__ q,
    float* __restrict__ kbuf, float* __restrict__ vbuf) {
  __shared__ float As[64][17];
  __shared__ float Bs[64][17];
  const int tid = threadIdx.x;
  const int m0 = blockIdx.y * 64;
  const int n0 = blockIdx.x * 64;
  const int tx = tid & 15, ty = tid >> 4;
  const int lrow = tid >> 2, lk0 = (tid & 3) * 4;
  float c[4][4] = {};
  for (int k0 = 0; k0 < D_; k0 += 16) {
    float4 fa = *reinterpret_cast<const float4*>(x + (size_t)(m0 + lrow) * D_ + k0 + lk0);
    float4 fb = *reinterpret_cast<const float4*>(w + (size_t)(n0 + lrow) * D_ + k0 + lk0);
    __syncthreads();
    As[lrow][lk0 + 0] = fa.x; As[lrow][lk0 + 1] = fa.y;
    As[lrow][lk0 + 2] = fa.z; As[lrow][lk0 + 3] = fa.w;
    Bs[lrow][lk0 + 0] = fb.x; Bs[lrow][lk0 + 1] = fb.y;
    Bs[lrow][lk0 + 2] = fb.z; Bs[lrow][lk0 + 3] = fb.w;
    __syncthreads();
#pragma unroll
    for (int kk = 0; kk < 16; ++kk) {
      float a[4], b[4];
#pragma unroll
      for (int i = 0; i < 4; ++i) a[i] = As[ty * 4 + i][kk];
#pragma unroll
      for (int j = 0; j < 4; ++j) b[j] = Bs[tx * 4 + j][kk];
#pragma unroll
      for (int i = 0; i < 4; ++i)
#pragma unroll
        for (int j = 0; j < 4; ++j) c[i][j] = fmaf(a[i], b[j], c[i][j]);
    }
  }
#pragma unroll
  for (int j = 0; j < 4; ++j) {
    const int n = n0 + tx * 4 + j;
    const float bb = bias[n];
    const int which = n >> 10, rem = n & 1023;
    const int hh = rem >> 6, dd = rem & 63;
    float* dst = (which == 0) ? q : (which == 1) ? kbuf : vbuf;
#pragma unroll
    for (int i = 0; i < 4; ++i) {
      const int m = m0 + ty * 4 + i;
      const int bb2 = m >> 11, ss = m & (S_ - 1);
      dst[(((size_t)(bb2 * H_ + hh)) * S_ + ss) * HD_ + dd] = c[i][j] + bb;
    }
  }
}

// ---------------------------------------------------------------------------
// K2: per (b,h): centroid, d2c[s], sq[s], d2cmax
// ---------------------------------------------------------------------------
__global__ __launch_bounds__(256) void k_centroid(
    const float* __restrict__ x, float* __restrict__ d2c,
    float* __restrict__ sqn, float* __restrict__ d2cmax) {
  const int bh = blockIdx.x, b = bh >> 4, h = bh & 15;
  const int tid = threadIdx.x;
  const int d = tid & 63, w = tid >> 6;
  __shared__ float cpart[4][64];
  __shared__ float cent[64];
  __shared__ float wmax[4];
  const float* xb = x + (size_t)b * S_ * D_ + h * HD_;
  float part = 0.f;
  for (int s = w; s < S_; s += 4) part += xb[(size_t)s * D_ + d];
  cpart[w][d] = part;
  __syncthreads();
  if (tid < 64)
    cent[tid] = (cpart[0][tid] + cpart[1][tid] + cpart[2][tid] + cpart[3][tid]) * (1.f / 2048.f);
  __syncthreads();
  const float cd = cent[d];
  float lmax = 0.f;
  for (int s = w; s < S_; s += 4) {
    float val = xb[(size_t)s * D_ + d];
    float df = val - cd;
    float s1 = wsum(df * df);
    float s2 = wsum(val * val);
    if (d == 0) {
      float r = sqrtf(s1);
      d2c[bh * S_ + s] = r;
      sqn[bh * S_ + s] = s2;
      lmax = fmaxf(lmax, r);
    }
  }
  if (d == 0) wmax[w] = lmax;
  __syncthreads();
  if (tid == 0) d2cmax[bh] = fmaxf(fmaxf(wmax[0], wmax[1]), fmaxf(wmax[2], wmax[3]));
}

// branch-free sorted insert (ascending top[0..9])
DI void insert10(float* top, float v) {
#pragma unroll
  for (int j = 9; j >= 1; --j) top[j] = fmaxf(fminf(v, top[j]), top[j - 1]);
  top[0] = fminf(v, top[0]);
}

// ---------------------------------------------------------------------------
// K3: per row s: mmd[s] = sqrt(10th-smallest of clamp(sq_s+sq_t-2*dot,0))
// one wave per row, 4 rows/block (same b,h)
// ---------------------------------------------------------------------------
__global__ __launch_bounds__(256) void k_kth(
    const float* __restrict__ x, const float* __restrict__ sqn,
    float* __restrict__ mmd) {
  const int bh = blockIdx.y, b = bh >> 4, h = bh & 15;
  const int s0 = blockIdx.x * 4;
  const int tid = threadIdx.x;
  const int w = tid >> 6, lane = tid & 63;
  __shared__ float Xt[128][65];
  __shared__ float sRow[4][64];
  const float* xb = x + (size_t)b * S_ * D_ + h * HD_;
  sRow[w][lane] = xb[(size_t)(s0 + w) * D_ + lane];
  const int s = s0 + w;
  const float sq_s = sqn[bh * S_ + s];
  float top[10];
#pragma unroll
  for (int i = 0; i < 10; ++i) top[i] = __builtin_inff();
  for (int t0 = 0; t0 < S_; t0 += 128) {
    __syncthreads();
    for (int it = 0; it < 8; ++it) {
      int g = it * 256 + tid;          // 2048 float4 = 128 rows x 16
      int r = g >> 4, d0 = (g & 15) * 4;
      float4 f = *reinterpret_cast<const float4*>(xb + (size_t)(t0 + r) * D_ + d0);
      Xt[r][d0] = f.x; Xt[r][d0 + 1] = f.y; Xt[r][d0 + 2] = f.z; Xt[r][d0 + 3] = f.w;
    }
    __syncthreads();
    float acc0 = 0.f, acc1 = 0.f;
    for (int dd = 0; dd < 64; ++dd) {
      float qq = sRow[w][dd];
      acc0 = fmaf(qq, Xt[lane][dd], acc0);
      acc1 = fmaf(qq, Xt[lane + 64][dd], acc1);
    }
    const int ta = t0 + lane, tb = t0 + 64 + lane;
    float v0 = fmaxf(sq_s + sqn[bh * S_ + ta] - 2.f * acc0, 0.f);
    float v1 = fmaxf(sq_s + sqn[bh * S_ + tb] - 2.f * acc1, 0.f);
    if (v0 < top[9]) insert10(top, v0);
    if (v1 < top[9]) insert10(top, v1);
  }
  // wave-level multiset merge: extract global 10 smallest
  float kth = 0.f;
  for (int it = 0; it < 10; ++it) {
    float m = wminr(top[0]);
    unsigned long long ball = __ballot(top[0] == m);
    int src = __ffsll(ball) - 1;
    if (lane == src) {
#pragma unroll
      for (int j = 0; j < 9; ++j) top[j] = top[j + 1];
      top[9] = __builtin_inff();
    }
    kth = m;
  }
  if (lane == 0) mmd[bh * S_ + s] = sqrtf(kth);
}

// ---------------------------------------------------------------------------
// K4: per (b,h) max over mmd
// ---------------------------------------------------------------------------
__global__ __launch_bounds__(256) void k_maxreduce(
    const float* __restrict__ src, float* __restrict__ dst) {
  const int bh = blockIdx.x, tid = threadIdx.x;
  float m = 0.f;
  for (int s = tid; s < S_; s += 256) m = fmaxf(m, src[bh * S_ + s]);
  __shared__ float red[256];
  red[tid] = m;
  __syncthreads();
  for (int o = 128; o > 0; o >>= 1) {
    if (tid < o) red[tid] = fmaxf(red[tid], red[tid + o]);
    __syncthreads();
  }
  if (tid == 0) dst[bh] = red[0];
}

// ---------------------------------------------------------------------------
// K5: tls = 0.7*d2c/(d2cmax+1e-8) + 0.3*mmd/(mmdmax+1e-8); top-675 -> mask
// index-stable tie-break matching jax.lax.top_k
// ---------------------------------------------------------------------------
__global__ __launch_bounds__(256) void k_topk(
    const float* __restrict__ d2c, const float* __restrict__ mmd,
    const float* __restrict__ d2cmax, const float* __restrict__ mmdmax,
    unsigned char* __restrict__ lmask) {
  const int bh = blockIdx.x, tid = threadIdx.x;
  __shared__ float vals[S_];
  __shared__ int red[256];
  const float dden = d2cmax[bh] + 1e-8f;
  const float mden = mmdmax[bh] + 1e-8f;
  for (int s = tid; s < S_; s += 256) {
    float lift = d2c[bh * S_ + s] / dden;
    float mn = mmd[bh * S_ + s] / mden;
    vals[s] = 0.7f * lift + 0.3f * mn;
  }
  __syncthreads();
  // binary search on float bits (all vals >= 0) for the 675th largest value
  unsigned lo = 0u, hi = 0x7f800000u;
  while (hi - lo > 1u) {
    unsigned mid = (lo + hi) >> 1;
    float T = __uint_as_float(mid);
    int cc = 0;
    for (int s = tid; s < S_; s += 256) cc += (vals[s] >= T);
    red[tid] = cc;
    __syncthreads();
    for (int o = 128; o > 0; o >>= 1) {
      if (tid < o) red[tid] += red[tid + o];
      __syncthreads();
    }
    int cnt = red[0];
    __syncthreads();
    if (cnt >= NKEEP) lo = mid; else hi = mid;
  }
  const float v675 = __uint_as_float(lo);
  int cc = 0;
  for (int s = tid; s < S_; s += 256) cc += (vals[s] > v675);
  red[tid] = cc;
  __syncthreads();
  for (int o = 128; o > 0; o >>= 1) {
    if (tid < o) red[tid] += red[tid + o];
    __syncthreads();
  }
  const int need = NKEEP - red[0];
  __syncthreads();
  for (int s = tid; s < S_; s += 256) {
    float vv = vals[s];
    int sel = vv > v675;
    if (!sel && vv == v675) {
      int r = 0;
      for (int t = 0; t < s; ++t) r += (vals[t] == v675);
      sel = (r < need);
    }
    lmask[bh * S_ + s] = (unsigned char)sel;
  }
}

// ---------------------------------------------------------------------------
// K6: scores + mask + softmax -> attn.  Flash-style two-pass.
// One block per (bh, 64-row tile). grid = 1024 blocks, XCD-swizzled so each
// XCD's L2 caches 4 bh worth of K (4 x 512 KB).
// Thread tile: 8 rows x 4 cols of the 64x128 score tile per K-tile.
// Pass A: online (m,l) per row in regs (base-2 domain, native v_exp_f32),
//         cross-lane merge over the 32 same-row lanes via shfl_xor.
// Pass B: recompute scores (identical FMA order -> identical values),
//         write exp2(s-m)*invl as coalesced float4 stores; masked -> 0.0f
//         (exact: row max >= diag >= 0, so exp2(-14427-m) underflows to 0,
//          matching the reference's exp(-10000-m) underflow).
// ---------------------------------------------------------------------------
__global__ __launch_bounds__(256, 3) void k_attn(
    const float* __restrict__ q, const float* __restrict__ k,
    const unsigned char* __restrict__ lmask, float* __restrict__ attn) {
  const int bid = blockIdx.x;
  const int wg = (bid & 7) * 128 + (bid >> 3);   // bijective XCD swizzle (1024 = 8*128)
  const int bh = wg >> 5;
  const int s0 = (wg & 31) * 64;
  const int tid = threadIdx.x;
  const int tx = tid & 31, ty = tid >> 5;

  __shared__ float Qt[64][68];          // transposed: Qt[dd][row]  (16B-aligned rows)
  __shared__ float Ks[128][65];         // Ks[col][dd]
  __shared__ unsigned char lm[S_];

  const float* qb = q + (size_t)bh * S_ * HD_;
  const float* kb = k + (size_t)bh * S_ * HD_;

  // stage Q (transposed) + landmark mask, once
  {
    const unsigned* lm32 = reinterpret_cast<const unsigned*>(lmask + bh * S_);
    unsigned* dl = reinterpret_cast<unsigned*>(lm);
    dl[tid] = lm32[tid];
    dl[tid + 256] = lm32[tid + 256];
#pragma unroll
    for (int it = 0; it < 4; ++it) {
      const int g = it * 256 + tid;
      const int r = g >> 4, d0 = (g & 15) * 4;
      float4 f = *reinterpret_cast<const float4*>(qb + (size_t)(s0 + r) * HD_ + d0);
      Qt[d0 + 0][r] = f.x; Qt[d0 + 1][r] = f.y;
      Qt[d0 + 2][r] = f.z; Qt[d0 + 3][r] = f.w;
    }
  }

  constexpr float SCL = 0.18033688011112042f;   // 0.125 * log2(e)
  constexpr float MB2 = -14426.950408889634f;   // -10000 * log2(e)

  const int row0 = ty * 8;
  const int col0 = tx * 4;
  const int rg0 = s0 + row0;

  float m[8], l[8], invl[8];
#pragma unroll
  for (int i = 0; i < 8; ++i) { m[i] = MB2; l[i] = 0.f; invl[i] = 0.f; }

  for (int pass = 0; pass < 2; ++pass) {
    for (int t = 0; t < 16; ++t) {
      const int t0 = t * 128;
      __syncthreads();
#pragma unroll
      for (int it = 0; it < 8; ++it) {
        const int g = it * 256 + tid;
        const int r = g >> 4, d0 = (g & 15) * 4;
        float4 f = *reinterpret_cast<const float4*>(kb + (size_t)(t0 + r) * HD_ + d0);
        Ks[r][d0 + 0] = f.x; Ks[r][d0 + 1] = f.y;
        Ks[r][d0 + 2] = f.z; Ks[r][d0 + 3] = f.w;
      }
      __syncthreads();

      float acc[8][4] = {};
      const float* ksp = &Ks[col0][0];
#pragma unroll 4
      for (int dd = 0; dd < 64; ++dd) {
        const float4 a0 = *reinterpret_cast<const float4*>(&Qt[dd][row0]);
        const float4 a1 = *reinterpret_cast<const float4*>(&Qt[dd][row0 + 4]);
        const float a[8] = {a0.x, a0.y, a0.z, a0.w, a1.x, a1.y, a1.z, a1.w};
        const float b[4] = {ksp[0 * 65 + dd], ksp[1 * 65 + dd],
                            ksp[2 * 65 + dd], ksp[3 * 65 + dd]};
#pragma unroll
        for (int i = 0; i < 8; ++i)
#pragma unroll
          for (int j = 0; j < 4; ++j) acc[i][j] = fmaf(a[i], b[j], acc[i][j]);
      }

      const int cg0 = t0 + col0;
      bool kc[4];
#pragma unroll
      for (int j = 0; j < 4; ++j) kc[j] = lm[cg0 + j] != 0;

      if (pass == 0) {
#pragma unroll
        for (int i = 0; i < 8; ++i) {
          const int rel0 = cg0 - (rg0 + i) + 64;   // keep iff 0 <= rel0+j <= 128
          float s[4];
#pragma unroll
          for (int j = 0; j < 4; ++j) {
            const bool kp = kc[j] || ((unsigned)(rel0 + j) <= 128u);
            s[j] = kp ? acc[i][j] * SCL : MB2;
          }
          const float tm = fmaxf(fmaxf(s[0], s[1]), fmaxf(s[2], s[3]));
          const float nm = fmaxf(m[i], tm);
          const float add = exp2f(s[0] - nm) + exp2f(s[1] - nm) +
                            exp2f(s[2] - nm) + exp2f(s[3] - nm);
          l[i] = l[i] * exp2f(m[i] - nm) + add;
          m[i] = nm;
        }
      } else {
        float* ap = attn + ((size_t)bh * S_ + rg0) * S_ + cg0;
#pragma unroll
        for (int i = 0; i < 8; ++i) {
          const int rel0 = cg0 - (rg0 + i) + 64;
          float o[4];
#pragma unroll
          for (int j = 0; j < 4; ++j) {
            const bool kp = kc[j] || ((unsigned)(rel0 + j) <= 128u);
            o[j] = kp ? exp2f(acc[i][j] * SCL - m[i]) * invl[i] : 0.f;
          }
          *reinterpret_cast<float4*>(ap + (size_t)i * S_) =
              make_float4(o[0], o[1], o[2], o[3]);
        }
      }
    }
    if (pass == 0) {
      // merge (m,l) across the 32 lanes sharing this row set (ty-group is a
      // 32-lane-aligned half-wave, shfl_xor offsets <=16 stay inside it)
#pragma unroll
      for (int i = 0; i < 8; ++i) {
        float mi = m[i], li = l[i];
#pragma unroll
        for (int off = 1; off <= 16; off <<= 1) {
          const float om = __shfl_xor(mi, off, 64);
          const float ol = __shfl_xor(li, off, 64);
          const float nm = fmaxf(mi, om);
          li = li * exp2f(mi - nm) + ol * exp2f(om - nm);
          mi = nm;
        }
        m[i] = mi; l[i] = li; invl[i] = 1.f / li;
      }
    }
  }
}

// ---------------------------------------------------------------------------
// K7: ao(b,s,h*64+d) = attn(bh,s,:) @ v(bh,:,d)   [attn f32]
// ---------------------------------------------------------------------------
__global__ __launch_bounds__(256) void k_av(
    const float* __restrict__ attn, const float* __restrict__ v,
    float* __restrict__ ao) {
  const int bh = blockIdx.y, b = bh >> 4, h = bh & 15;
  const int s0 = blockIdx.x * 64;
  const int tid = threadIdx.x, tx = tid & 15, ty = tid >> 4;
  __shared__ float As[64][17];
  __shared__ float Bs[16][65];
  const float* ab = attn + (size_t)bh * S_ * S_;
  const float* vb = v + (size_t)bh * S_ * HD_;
  float c[4][4] = {};
  const int arow = tid >> 2, ak0 = (tid & 3) * 4;
  const int vrow = tid >> 4, vd0 = (tid & 15) * 4;
  for (int t0 = 0; t0 < S_; t0 += 16) {
    float4 fa = *reinterpret_cast<const float4*>(ab + (size_t)(s0 + arow) * S_ + t0 + ak0);
    float4 f = *reinterpret_cast<const float4*>(vb + (size_t)(t0 + vrow) * HD_ + vd0);
    __syncthreads();
    As[arow][ak0 + 0] = fa.x; As[arow][ak0 + 1] = fa.y;
    As[arow][ak0 + 2] = fa.z; As[arow][ak0 + 3] = fa.w;
    Bs[vrow][vd0] = f.x; Bs[vrow][vd0 + 1] = f.y; Bs[vrow][vd0 + 2] = f.z; Bs[vrow][vd0 + 3] = f.w;
    __syncthreads();
#pragma unroll
    for (int kk = 0; kk < 16; ++kk) {
      float a[4], bb[4];
#pragma unroll
      for (int i = 0; i < 4; ++i) a[i] = As[ty * 4 + i][kk];
#pragma unroll
      for (int j = 0; j < 4; ++j) bb[j] = Bs[kk][tx * 4 + j];
#pragma unroll
      for (int i = 0; i < 4; ++i)
#pragma unroll
        for (int j = 0; j < 4; ++j) c[i][j] = fmaf(a[i], bb[j], c[i][j]);
    }
  }
#pragma unroll
  for (int i = 0; i < 4; ++i) {
    const int ss = s0 + ty * 4 + i;
    float* dst = ao + (size_t)(b * S_ + ss) * D_ + h * HD_;
#pragma unroll
    for (int j = 0; j < 4; ++j) dst[tx * 4 + j] = c[i][j];
  }
}

// ---------------------------------------------------------------------------
// K8: y = ao @ out_w^T + out_b  -> f32 d_out
// ---------------------------------------------------------------------------
__global__ __launch_bounds__(256) void k_gemm_out(
    const float* __restrict__ a, const float* __restrict__ w,
    const float* __restrict__ bias, float* __restrict__ y) {
  __shared__ float As[64][17];
  __shared__ float Bs[64][17];
  const int tid = threadIdx.x;
  const int m0 = blockIdx.y * 64;
  const int n0 = blockIdx.x * 64;
  const int tx = tid & 15, ty = tid >> 4;
  const int lrow = tid >> 2, lk0 = (tid & 3) * 4;
  float c[4][4] = {};
  for (int k0 = 0; k0 < D_; k0 += 16) {
    float4 fa = *reinterpret_cast<const float4*>(a + (size_t)(m0 + lrow) * D_ + k0 + lk0);
    float4 fb = *reinterpret_cast<const float4*>(w + (size_t)(n0 + lrow) * D_ + k0 + lk0);
    __syncthreads();
    As[lrow][lk0 + 0] = fa.x; As[lrow][lk0 + 1] = fa.y;
    As[lrow][lk0 + 2] = fa.z; As[lrow][lk0 + 3] = fa.w;
    Bs[lrow][lk0 + 0] = fb.x; Bs[lrow][lk0 + 1] = fb.y;
    Bs[lrow][lk0 + 2] = fb.z; Bs[lrow][lk0 + 3] = fb.w;
    __syncthreads();
#pragma unroll
    for (int kk = 0; kk < 16; ++kk) {
      float av[4], bv[4];
#pragma unroll
      for (int i = 0; i < 4; ++i) av[i] = As[ty * 4 + i][kk];
#pragma unroll
      for (int j = 0; j < 4; ++j) bv[j] = Bs[tx * 4 + j][kk];
#pragma unroll
      for (int i = 0; i < 4; ++i)
#pragma unroll
        for (int j = 0; j < 4; ++j) c[i][j] = fmaf(av[i], bv[j], c[i][j]);
    }
  }
#pragma unroll
  for (int j = 0; j < 4; ++j) {
    const int n = n0 + tx * 4 + j;
    const float bb = bias[n];
#pragma unroll
    for (int i = 0; i < 4; ++i) {
      const int m = m0 + ty * 4 + i;
      y[(size_t)m * D_ + n] = c[i][j] + bb;
    }
  }
}

extern "C" void kernel_launch(void* const* d_in, const int* in_sizes, int n_in,
                              void* d_out, int out_size, void* d_ws, size_t ws_size,
                              hipStream_t stream) {
  const float* x = (const float*)d_in[0];
  const float* qkv_w = (const float*)d_in[1];
  const float* qkv_b = (const float*)d_in[2];
  const float* out_w = (const float*)d_in[3];
  const float* out_b = (const float*)d_in[4];

  constexpr size_t QN = (size_t)BH_ * S_ * HD_;  // 4,194,304
  float* ws = (float*)d_ws;
  float* q = ws;
  float* kbuf = q + QN;
  float* vbuf = kbuf + QN;
  float* ao = vbuf + QN;                 // (B,S,D) f32
  float* d2c = ao + QN;                  // (BH,S)
  float* sqn = d2c + BH_ * S_;
  float* mmd = sqn + BH_ * S_;
  float* d2cmax = mmd + BH_ * S_;        // (BH)
  float* mmdmax = d2cmax + BH_;
  unsigned char* lmask = (unsigned char*)(mmdmax + BH_);  // (BH,S) bytes

  float* outy = (float*)d_out;           // (B,S,D) f32
  float* attn = outy + QN;               // (BH,S,S) f32

  k_gemm_qkv<<<dim3(48, 64), dim3(256), 0, stream>>>(x, qkv_w, qkv_b, q, kbuf, vbuf);
  k_centroid<<<dim3(32), dim3(256), 0, stream>>>(x, d2c, sqn, d2cmax);
  k_kth<<<dim3(512, 32), dim3(256), 0, stream>>>(x, sqn, mmd);
  k_maxreduce<<<dim3(32), dim3(256), 0, stream>>>(mmd, mmdmax);
  k_topk<<<dim3(32), dim3(256), 0, stream>>>(d2c, mmd, d2cmax, mmdmax, lmask);
  k_attn<<<dim3(1024), dim3(256), 0, stream>>>(q, kbuf, lmask, attn);
  k_av<<<dim3(32, 32), dim3(256), 0, stream>>>(attn, vbuf, ao);
  k_gemm_out<<<dim3(16, 64), dim3(256), 0, stream>>>(ao, out_w, out_b, outy);
}